// Round 5
// baseline (793.254 us; speedup 1.0000x reference)
//
#include <hip/hip_runtime.h>
#include <stdint.h>

#define SCALE 0.17677669529663687f  // 32^-0.5

typedef __attribute__((ext_vector_type(8))) short short8;
typedef __attribute__((ext_vector_type(4))) float floatx4;

__device__ __forceinline__ unsigned short f2bf(float f) {
    union { float f; unsigned u; } v; v.f = f;
    unsigned r = (v.u + 0x7fffu + ((v.u >> 16) & 1u)) >> 16;  // RNE
    return (unsigned short)r;
}

// ---------- prep: transpose weights to bf16 (W^T rows = output cols, contiguous K) ----------
__global__ void prep_weights(const float* __restrict__ qkv_w,
                             const float* __restrict__ proj_w,
                             unsigned short* __restrict__ qkv_wt,
                             unsigned short* __restrict__ proj_wt) {
    int i = blockIdx.x * blockDim.x + threadIdx.x;
    const int nq = 1152 * 384;
    const int np = 384 * 384;
    if (i < nq) {
        int r = i / 384, c = i - r * 384;          // qkv_wt[r][c] = qkv_w[c][r]
        qkv_wt[i] = f2bf(qkv_w[c * 1152 + r]);
    } else if (i < nq + np) {
        int o = i - nq;
        int r = o / 384, c = o - r * 384;
        proj_wt[o] = f2bf(proj_w[c * 384 + r]);
    }
}

// ---------- prep: relative-position bias table bt[h][i][j], 12x64x64 fp32 ----------
__global__ void prep_bias(const float* __restrict__ w1, const float* __restrict__ b1,
                          const float* __restrict__ w2, const float* __restrict__ b2,
                          float* __restrict__ bt) {
    int t = blockIdx.x * blockDim.x + threadIdx.x;  // 4096 threads
    int i = t >> 6, j = t & 63;
    float r0 = (float)((i >> 4) - (j >> 4));
    float r1 = (float)(((i >> 2) & 3) - ((j >> 2) & 3));
    float r2 = (float)((i & 3) - (j & 3));
    float acc[12];
#pragma unroll
    for (int h = 0; h < 12; ++h) acc[h] = b2[h];
    for (int u = 0; u < 64; ++u) {
        float hv = r0 * w1[u] + r1 * w1[64 + u] + r2 * w1[128 + u] + b1[u];
        hv = fmaxf(hv, 0.f);
#pragma unroll
        for (int h = 0; h < 12; ++h) acc[h] += hv * w2[u * 12 + h];
    }
    for (int h = 0; h < 12; ++h) bt[(h << 12) + (i << 6) + j] = acc[h];
}

// ---------- fused window attention: one block = one window, 384 threads / 6 waves ----------
// Single-phase pipeline: iter p = { B1(p) || B23(p-1) || proj(p-2) } barrier.
// Three independent instruction streams per barrier interval; 8 barriers total.
// ql/kl/vt double-buffered across pairs; osl double-buffered; pb strictly same-wave.
#define XP  392   // xs row stride (384+8 shorts)
#define QKP 40    // q/k row stride (32+8)
#define VTP 72    // vT row stride (64+8)
#define PBP 72    // P row stride (64+8)
#define OSP 72    // osl row stride (64+8): 64 cols = 2 heads x 32d

__launch_bounds__(384, 2)
__global__ void win_attn(const float* __restrict__ x,
                         const unsigned short* __restrict__ qkv_wt,
                         const float* __restrict__ qkv_b,
                         const unsigned short* __restrict__ proj_wt,
                         const float* __restrict__ proj_b,
                         const float* __restrict__ bt,
                         float* __restrict__ out) {
    __shared__ unsigned short xs[64 * XP];            // x window bf16       50176 B
    __shared__ unsigned short ql[2][2][64 * QKP];     // q [pairbuf][head]   20480 B
    __shared__ unsigned short kl[2][2][64 * QKP];     // k                   20480 B
    __shared__ unsigned short vt[2][2][32 * VTP];     // v^T                 18432 B
    __shared__ unsigned short pb[2][4][16 * PBP];     // P [head][rowblock]  18432 B
    __shared__ unsigned short osl[2][64 * OSP];       // O pair-slice, dbuf  18432 B
                                                      // total 146432 B -> 1 block/CU
    const int tid  = threadIdx.x;
    const int lane = tid & 63;
    const int w    = tid >> 6;     // wave 0..5
    const int l15  = lane & 15;
    const int quad = lane >> 4;
    const int b    = blockIdx.x;

    // ---- stage x -> bf16 LDS (coalesced float4) ----
    const float* xb = x + (size_t)b * (64 * 384);
#pragma unroll
    for (int it = 0; it < 16; ++it) {
        int idx = it * 384 + tid;
        int row = idx / 96;                          // 96 float4 per row
        int c4  = idx - row * 96;
        const float4 v = *reinterpret_cast<const float4*>(xb + row * 384 + c4 * 4);
        uint2 pk;
        pk.x = (unsigned)f2bf(v.x) | ((unsigned)f2bf(v.y) << 16);
        pk.y = (unsigned)f2bf(v.z) | ((unsigned)f2bf(v.w) << 16);
        *reinterpret_cast<uint2*>(&xs[row * XP + c4 * 4]) = pk;
    }
    __syncthreads();

    // B1 role: wave w -> (q/k/v) = w>>1, d-half = w&1; both heads of the pair.
    const int j3 = w >> 1;
    const int d2 = w & 1;
    // proj role: waves 0-3 own 5 N-tiles, waves 4-5 own 2 (balances extra B23 on 4,5)
    const int ntile = (w < 4) ? 5 : 2;
    const int t0    = (w < 4) ? 5 * w : (20 + 2 * (w - 4));
    // B23 roles (fixed per wave): task0 = (h0, rb0); task1 = (1, w-2) for waves 4,5
    const int h0  = (w < 4) ? 0 : 1;
    const int rb0 = (w < 4) ? w : (w - 4);

    const floatx4 zf4 = {0.f, 0.f, 0.f, 0.f};
    floatx4 acc2[5][4];            // persistent proj accumulator
#pragma unroll
    for (int jj = 0; jj < 5; ++jj)
#pragma unroll
        for (int m = 0; m < 4; ++m) acc2[jj][m] = zf4;

// ---- proj(PP): acc2 += osl[PP&1] @ proj_wt[:, PP*64 .. PP*64+64] ----
#define PROJ_STEP(PP)                                                                   \
    {                                                                                   \
        const int buf_ = (PP) & 1;                                                      \
        short8 a2_[4][2];                                                               \
        _Pragma("unroll")                                                               \
        for (int m = 0; m < 4; ++m)                                                     \
            _Pragma("unroll")                                                           \
            for (int k2 = 0; k2 < 2; ++k2)                                              \
                a2_[m][k2] = *reinterpret_cast<const short8*>(                          \
                    &osl[buf_][(16 * m + l15) * OSP + k2 * 32 + quad * 8]);             \
        _Pragma("unroll")                                                               \
        for (int jj = 0; jj < 5; ++jj)                                                  \
            if (jj < ntile) {                                                           \
                const unsigned short* pw =                                              \
                    proj_wt + (size_t)((t0 + jj) * 16 + l15) * 384 + (PP) * 64;         \
                const short8 b20 = *reinterpret_cast<const short8*>(pw + quad * 8);     \
                const short8 b21 = *reinterpret_cast<const short8*>(pw + 32 + quad * 8);\
                _Pragma("unroll")                                                       \
                for (int m = 0; m < 4; ++m) {                                           \
                    acc2[jj][m] = __builtin_amdgcn_mfma_f32_16x16x32_bf16(              \
                        a2_[m][0], b20, acc2[jj][m], 0, 0, 0);                          \
                    acc2[jj][m] = __builtin_amdgcn_mfma_f32_16x16x32_bf16(              \
                        a2_[m][1], b21, acc2[jj][m], 0, 0, 0);                          \
                }                                                                       \
            }                                                                           \
    }

// ---- B23 task: S = qk^T*scale+bias, softmax, O = P@V -> osl[(PP)&1] ----
#define B23_TASK(H, RB, PP, RBUF)                                                       \
    {                                                                                   \
        const int hg_ = 2 * (PP) + (H);                                                 \
        const short8 aq_ = *reinterpret_cast<const short8*>(                            \
            &ql[RBUF][H][(16 * (RB) + l15) * QKP + quad * 8]);                          \
        floatx4 s4_[4];                                                                 \
        _Pragma("unroll")                                                               \
        for (int c = 0; c < 4; ++c) {                                                   \
            const short8 bk_ = *reinterpret_cast<const short8*>(                        \
                &kl[RBUF][H][(16 * c + l15) * QKP + quad * 8]);                         \
            s4_[c] = __builtin_amdgcn_mfma_f32_16x16x32_bf16(aq_, bk_, zf4, 0, 0, 0);   \
        }                                                                               \
        const float* bth_ = bt + ((size_t)hg_ << 12);                                   \
        float rs_[4];                                                                   \
        _Pragma("unroll")                                                               \
        for (int r = 0; r < 4; ++r) {                                                   \
            const int n_ = 16 * (RB) + quad * 4 + r;                                    \
            _Pragma("unroll")                                                           \
            for (int c = 0; c < 4; ++c)                                                 \
                s4_[c][r] = s4_[c][r] * SCALE + bth_[(n_ << 6) + 16 * c + l15];         \
            float m0_ = fmaxf(fmaxf(s4_[0][r], s4_[1][r]), fmaxf(s4_[2][r], s4_[3][r]));\
            _Pragma("unroll")                                                           \
            for (int sh = 1; sh < 16; sh <<= 1) m0_ = fmaxf(m0_, __shfl_xor(m0_, sh, 16)); \
            float p0_ = 0.f;                                                            \
            _Pragma("unroll")                                                           \
            for (int c = 0; c < 4; ++c) {                                               \
                float pv_ = __expf(s4_[c][r] - m0_);                                    \
                s4_[c][r] = pv_;                                                        \
                p0_ += pv_;                                                             \
            }                                                                           \
            _Pragma("unroll")                                                           \
            for (int sh = 1; sh < 16; sh <<= 1) p0_ += __shfl_xor(p0_, sh, 16);         \
            rs_[r] = 1.f / p0_;                                                         \
            _Pragma("unroll")                                                           \
            for (int c = 0; c < 4; ++c)                                                 \
                pb[H][RB][(quad * 4 + r) * PBP + 16 * c + l15] = f2bf(s4_[c][r]);       \
        }                                                                               \
        short8 ap_[2];                                                                  \
        _Pragma("unroll")                                                               \
        for (int kkp = 0; kkp < 2; ++kkp)                                               \
            ap_[kkp] = *reinterpret_cast<const short8*>(                                \
                &pb[H][RB][l15 * PBP + kkp * 32 + quad * 8]);                           \
        _Pragma("unroll")                                                               \
        for (int t = 0; t < 2; ++t) {                                                   \
            floatx4 oacc_ = zf4;                                                        \
            _Pragma("unroll")                                                           \
            for (int kkp = 0; kkp < 2; ++kkp) {                                         \
                const short8 bv_ = *reinterpret_cast<const short8*>(                    \
                    &vt[RBUF][H][(16 * t + l15) * VTP + kkp * 32 + quad * 8]);          \
                oacc_ = __builtin_amdgcn_mfma_f32_16x16x32_bf16(ap_[kkp], bv_, oacc_, 0, 0, 0); \
            }                                                                           \
            _Pragma("unroll")                                                           \
            for (int r = 0; r < 4; ++r)                                                 \
                osl[(PP) & 1][(16 * (RB) + quad * 4 + r) * OSP + (H) * 32 + 16 * t + l15] = \
                    f2bf(oacc_[r] * rs_[r]);                                            \
        }                                                                               \
    }

#pragma unroll 1
    for (int p = 0; p < 6; ++p) {
        const int ob = p & 1;
        // ======== B1(p): q,k,v for heads 2p, 2p+1 -> buffers [ob] ========
        {
            floatx4 acc[2][4];
#pragma unroll
            for (int hh = 0; hh < 2; ++hh)
#pragma unroll
                for (int m = 0; m < 4; ++m) acc[hh][m] = zf4;

            int colbase[2];
#pragma unroll
            for (int hh = 0; hh < 2; ++hh)
                colbase[hh] = j3 * 384 + (2 * p + hh) * 32 + d2 * 16;
            const unsigned short* wcol0 = qkv_wt + (size_t)(colbase[0] + l15) * 384;
            const unsigned short* wcol1 = qkv_wt + (size_t)(colbase[1] + l15) * 384;

#pragma unroll
            for (int kk = 0; kk < 12; ++kk) {
                short8 a[4];
#pragma unroll
                for (int m = 0; m < 4; ++m)
                    a[m] = *reinterpret_cast<const short8*>(
                        &xs[(16 * m + l15) * XP + kk * 32 + quad * 8]);
                const short8 bf0 = *reinterpret_cast<const short8*>(wcol0 + kk * 32 + quad * 8);
                const short8 bf1 = *reinterpret_cast<const short8*>(wcol1 + kk * 32 + quad * 8);
#pragma unroll
                for (int m = 0; m < 4; ++m) {
                    acc[0][m] = __builtin_amdgcn_mfma_f32_16x16x32_bf16(a[m], bf0, acc[0][m], 0, 0, 0);
                    acc[1][m] = __builtin_amdgcn_mfma_f32_16x16x32_bf16(a[m], bf1, acc[1][m], 0, 0, 0);
                }
            }
            // epilogue: +bias; q/k row-major, v transposed (packed 8B stores)
#pragma unroll
            for (int hh = 0; hh < 2; ++hh) {
                const float bc = qkv_b[colbase[hh] + l15];
                if (j3 < 2) {
                    unsigned short* dst = (j3 == 0) ? ql[ob][hh] : kl[ob][hh];
#pragma unroll
                    for (int m = 0; m < 4; ++m)
#pragma unroll
                        for (int r = 0; r < 4; ++r)
                            dst[(16 * m + quad * 4 + r) * QKP + d2 * 16 + l15] =
                                f2bf(acc[hh][m][r] + bc);
                } else {
#pragma unroll
                    for (int m = 0; m < 4; ++m) {
                        uint2 pk;
                        pk.x = (unsigned)f2bf(acc[hh][m][0] + bc) | ((unsigned)f2bf(acc[hh][m][1] + bc) << 16);
                        pk.y = (unsigned)f2bf(acc[hh][m][2] + bc) | ((unsigned)f2bf(acc[hh][m][3] + bc) << 16);
                        *reinterpret_cast<uint2*>(
                            &vt[ob][hh][(d2 * 16 + l15) * VTP + 16 * m + quad * 4]) = pk;
                    }
                }
            }
        }
        // ======== B23(p-1): reads buffers [ob^1], writes osl[(p-1)&1] ========
        if (p >= 1) {
            const int rob = ob ^ 1;
            B23_TASK(h0, rb0, (p - 1), rob);
            if (w >= 4) B23_TASK(1, (w - 2), (p - 1), rob);
        }
        // ======== proj(p-2): reads osl[p&1] ========
        if (p >= 2) PROJ_STEP(p - 2);
        __syncthreads();
    }

    // ======== epilogue: B23(5), proj(4), barrier, proj(5) ========
    {
        B23_TASK(h0, rb0, 5, 1);
        if (w >= 4) B23_TASK(1, (w - 2), 5, 1);
        PROJ_STEP(4);
        __syncthreads();
        PROJ_STEP(5);
    }

    // ======== out = acc2 + proj_b ========
    float* ob_ptr = out + (size_t)b * (64 * 384);
#pragma unroll
    for (int jj = 0; jj < 5; ++jj)
        if (jj < ntile) {
            const int col = (t0 + jj) * 16 + l15;
            const float pbias = proj_b[col];
#pragma unroll
            for (int m = 0; m < 4; ++m)
#pragma unroll
                for (int r = 0; r < 4; ++r)
                    ob_ptr[(16 * m + quad * 4 + r) * 384 + col] = acc2[jj][m][r] + pbias;
        }
#undef PROJ_STEP
#undef B23_TASK
}

extern "C" void kernel_launch(void* const* d_in, const int* in_sizes, int n_in,
                              void* d_out, int out_size, void* d_ws, size_t ws_size,
                              hipStream_t stream) {
    const float* x      = (const float*)d_in[0];
    const float* qkv_w  = (const float*)d_in[1];
    const float* qkv_b  = (const float*)d_in[2];
    const float* proj_w = (const float*)d_in[3];
    const float* proj_b = (const float*)d_in[4];
    const float* mlp_w1 = (const float*)d_in[5];
    const float* mlp_b1 = (const float*)d_in[6];
    const float* mlp_w2 = (const float*)d_in[7];
    const float* mlp_b2 = (const float*)d_in[8];
    float* out = (float*)d_out;

    // workspace layout (re-written every launch; harness poisons ws)
    unsigned short* qkv_wt  = (unsigned short*)d_ws;              // 1152*384 bf16
    unsigned short* proj_wt = qkv_wt + 1152 * 384;                // 384*384 bf16
    float*          bt      = (float*)(proj_wt + 384 * 384);      // 12*64*64 fp32

    prep_weights<<<2304, 256, 0, stream>>>(qkv_w, proj_w, qkv_wt, proj_wt);
    prep_bias<<<16, 256, 0, stream>>>(mlp_w1, mlp_b1, mlp_w2, mlp_b2, bt);
    win_attn<<<2048, 384, 0, stream>>>(x, qkv_wt, qkv_b, proj_wt, proj_b, bt, out);
}